// Round 2
// baseline (717.907 us; speedup 1.0000x reference)
//
#include <hip/hip_runtime.h>
#include <hip/hip_bf16.h>
#include <stdint.h>

typedef __attribute__((ext_vector_type(8))) short short8;
typedef __attribute__((ext_vector_type(4))) float f32x4;

#define S_LEN   4096
#define HID_DIM 2048
#define NHEAD   16
#define NKV     4
#define DHEAD   128
#define QPG     4
#define GROUP   768   // (QPG+2)*DHEAD
#define TOTAL   3072  // NKV*GROUP

__device__ __forceinline__ ushort f2bf(float f) {
    union { float f; uint32_t u; } c; c.f = f;
    uint32_t u = c.u;
    u += 0x7fff + ((u >> 16) & 1);   // RNE
    return (ushort)(u >> 16);
}

// ---------------------------------------------------------------------------
// fp32 -> bf16 convert (vectorized, grid-stride)
// ---------------------------------------------------------------------------
__global__ __launch_bounds__(256)
void cvt_f32_bf16(const float* __restrict__ src, ushort* __restrict__ dst, int n4)
{
    int i = blockIdx.x * blockDim.x + threadIdx.x;
    int stride = gridDim.x * blockDim.x;
    for (; i < n4; i += stride) {
        float4 v = ((const float4*)src)[i];
        ushort4 o;
        o.x = f2bf(v.x); o.y = f2bf(v.y); o.z = f2bf(v.z); o.w = f2bf(v.w);
        ((ushort4*)dst)[i] = o;
    }
}

// ---------------------------------------------------------------------------
// C[M,N] = A[M,K] * B[N,K]^T   (bf16 in, fp32 accum, OutT out)
// 128x128 tile, BK=32, 256 threads = 4 waves in 2x2, 4x4 16x16x32 frags/wave
// ---------------------------------------------------------------------------
__device__ __forceinline__ void store_c(ushort* C, size_t idx, float v) { C[idx] = f2bf(v); }
__device__ __forceinline__ void store_c(float*  C, size_t idx, float v) { C[idx] = v; }

template <typename OutT>
__global__ __launch_bounds__(256, 2)
void gemm_bt(const ushort* __restrict__ A, const ushort* __restrict__ B,
             OutT* __restrict__ C, int M, int N, int K)
{
    __shared__ alignas(16) ushort Asl[128][40];  // +8 pad: row stride 80B, 2-way (free)
    __shared__ alignas(16) ushort Bsl[128][40];

    const int tid  = threadIdx.x;
    const int wave = tid >> 6;
    const int lane = tid & 63;
    const int quad = lane >> 4;
    const int l15  = lane & 15;
    const int wr   = wave >> 1;      // wave row (0/1) -> 64 rows
    const int wc   = wave & 1;       // wave col (0/1) -> 64 cols
    const int m0   = blockIdx.y * 128;
    const int n0   = blockIdx.x * 128;

    f32x4 acc[4][4];
#pragma unroll
    for (int i = 0; i < 4; i++)
#pragma unroll
        for (int j = 0; j < 4; j++) acc[i][j] = (f32x4)0.0f;

    for (int kb = 0; kb < K; kb += 32) {
        __syncthreads();
#pragma unroll
        for (int r = 0; r < 2; r++) {
            int idx = tid + r * 256;        // 0..511
            int row = idx >> 2;             // 4 chunks per row
            int c8  = idx & 3;
            const ushort* ga = A + (size_t)(m0 + row) * K + kb + c8 * 8;
            *(float4*)(&Asl[row][c8 * 8]) = *(const float4*)ga;
            const ushort* gb = B + (size_t)(n0 + row) * K + kb + c8 * 8;
            *(float4*)(&Bsl[row][c8 * 8]) = *(const float4*)gb;
        }
        __syncthreads();

        short8 af[4], bf[4];
#pragma unroll
        for (int i = 0; i < 4; i++)
            af[i] = *(const short8*)(&Asl[wr * 64 + i * 16 + l15][quad * 8]);
#pragma unroll
        for (int j = 0; j < 4; j++)
            bf[j] = *(const short8*)(&Bsl[wc * 64 + j * 16 + l15][quad * 8]);
#pragma unroll
        for (int i = 0; i < 4; i++)
#pragma unroll
            for (int j = 0; j < 4; j++)
                acc[i][j] = __builtin_amdgcn_mfma_f32_16x16x32_bf16(
                    af[i], bf[j], acc[i][j], 0, 0, 0);
    }

    // epilogue: C/D layout col=lane&15, row=quad*4+reg
#pragma unroll
    for (int i = 0; i < 4; i++)
#pragma unroll
        for (int j = 0; j < 4; j++)
#pragma unroll
            for (int r = 0; r < 4; r++) {
                int row = m0 + wr * 64 + i * 16 + quad * 4 + r;
                int col = n0 + wc * 64 + j * 16 + l15;
                store_c(C, (size_t)row * N + col, acc[i][j][r]);
            }
}

// ---------------------------------------------------------------------------
// Causal GQA flash attention. qkv: [S, TOTAL] bf16 (per kv-group g: 4 q heads,
// then k, then v). out: [S, NH*DHEAD] bf16.
// Block: 1 head x 128 q-rows. 4 waves x 32 rows each. K-tile = 64.
// ---------------------------------------------------------------------------
__global__ __launch_bounds__(256, 2)
void flash_attn(const ushort* __restrict__ qkv, ushort* __restrict__ out)
{
    const int head = blockIdx.y;          // 0..15
    const int g    = head >> 2;
    const int qh   = head & 3;
    const int qt   = gridDim.x - 1 - blockIdx.x;  // heavy tiles first
    const int q0   = qt * 128;

    const int tid  = threadIdx.x;
    const int wave = tid >> 6;
    const int lane = tid & 63;
    const int quad = lane >> 4;
    const int l15  = lane & 15;

    __shared__ alignas(16) ushort Kl[64][136];    // [j][d], pad 8
    __shared__ alignas(16) ushort Vt[128][72];    // [d][j] transposed, pad 8
    __shared__ alignas(16) ushort Pl[4][32][72];  // per-wave P buffer

    // Q fragments resident: 32 rows per wave, D=128 (4 k-steps of 32)
    short8 qf[2][4];
#pragma unroll
    for (int mi = 0; mi < 2; mi++) {
        int row = q0 + wave * 32 + mi * 16 + l15;
        const ushort* qp = qkv + (size_t)row * TOTAL + g * GROUP + qh * DHEAD + quad * 8;
#pragma unroll
        for (int ks = 0; ks < 4; ks++)
            qf[mi][ks] = *(const short8*)(qp + ks * 32);
    }

    f32x4 o[2][8];
#pragma unroll
    for (int mi = 0; mi < 2; mi++)
#pragma unroll
        for (int df = 0; df < 8; df++) o[mi][df] = (f32x4)0.0f;

    float m_run[2][4], l_run[2][4];
#pragma unroll
    for (int mi = 0; mi < 2; mi++)
#pragma unroll
        for (int r = 0; r < 4; r++) { m_run[mi][r] = -INFINITY; l_run[mi][r] = 0.0f; }

    const float scale = 0.088388347648318447f;  // 1/sqrt(128)
    const int ntiles = q0 / 64 + 2;

    for (int t = 0; t < ntiles; t++) {
        const int j0 = t * 64;
        __syncthreads();   // previous compute done before restaging
        // stage K[64][128] and V^T[128][64]: 1024 16B chunks, 4/thread
#pragma unroll
        for (int r = 0; r < 4; r++) {
            int c   = tid + r * 256;   // 0..1023
            int row = c >> 4;          // j within tile
            int c8  = c & 15;          // d-chunk
            const ushort* gk = qkv + (size_t)(j0 + row) * TOTAL + g * GROUP + QPG * DHEAD + c8 * 8;
            *(float4*)(&Kl[row][c8 * 8]) = *(const float4*)gk;
            const ushort* gv = qkv + (size_t)(j0 + row) * TOTAL + g * GROUP + (QPG + 1) * DHEAD + c8 * 8;
            float4 vv = *(const float4*)gv;
            const ushort* tv = (const ushort*)&vv;
#pragma unroll
            for (int u = 0; u < 8; u++) Vt[c8 * 8 + u][row] = tv[u];
        }
        __syncthreads();

        // S = Q K^T
        f32x4 sacc[2][4];
#pragma unroll
        for (int mi = 0; mi < 2; mi++)
#pragma unroll
            for (int ni = 0; ni < 4; ni++) sacc[mi][ni] = (f32x4)0.0f;
#pragma unroll
        for (int ni = 0; ni < 4; ni++) {
#pragma unroll
            for (int ks = 0; ks < 4; ks++) {
                short8 kf = *(const short8*)(&Kl[ni * 16 + l15][ks * 32 + quad * 8]);
#pragma unroll
                for (int mi = 0; mi < 2; mi++)
                    sacc[mi][ni] = __builtin_amdgcn_mfma_f32_16x16x32_bf16(
                        qf[mi][ks], kf, sacc[mi][ni], 0, 0, 0);
            }
        }

        // mask + online softmax (row = quad*4 + r, replicated over 16 lanes)
#pragma unroll
        for (int mi = 0; mi < 2; mi++) {
            float alpha[4];
#pragma unroll
            for (int r = 0; r < 4; r++) {
                int row_g = q0 + wave * 32 + mi * 16 + quad * 4 + r;
                float mx = -3e38f;
#pragma unroll
                for (int ni = 0; ni < 4; ni++) {
                    int col_g = j0 + ni * 16 + l15;
                    float s = sacc[mi][ni][r] * scale;
                    s = (col_g > row_g) ? -3e38f : s;
                    sacc[mi][ni][r] = s;
                    mx = fmaxf(mx, s);
                }
                mx = fmaxf(mx, __shfl_xor(mx, 1));
                mx = fmaxf(mx, __shfl_xor(mx, 2));
                mx = fmaxf(mx, __shfl_xor(mx, 4));
                mx = fmaxf(mx, __shfl_xor(mx, 8));
                float mn = fmaxf(m_run[mi][r], mx);
                float al = __expf(m_run[mi][r] - mn);   // -inf -> 0 first tile
                float rs = 0.0f;
#pragma unroll
                for (int ni = 0; ni < 4; ni++) {
                    float p = __expf(sacc[mi][ni][r] - mn);
                    sacc[mi][ni][r] = p;
                    rs += p;
                }
                rs += __shfl_xor(rs, 1);
                rs += __shfl_xor(rs, 2);
                rs += __shfl_xor(rs, 4);
                rs += __shfl_xor(rs, 8);
                l_run[mi][r] = l_run[mi][r] * al + rs;
                m_run[mi][r] = mn;
                alpha[r] = al;
            }
#pragma unroll
            for (int df = 0; df < 8; df++)
#pragma unroll
                for (int r = 0; r < 4; r++) o[mi][df][r] *= alpha[r];
            // P: C-layout -> LDS (bf16)
#pragma unroll
            for (int ni = 0; ni < 4; ni++)
#pragma unroll
                for (int r = 0; r < 4; r++)
                    Pl[wave][mi * 16 + quad * 4 + r][ni * 16 + l15] =
                        f2bf(sacc[mi][ni][r]);
        }
        __syncthreads();   // drain P writes before PV reads

        // O += P V
#pragma unroll
        for (int ks = 0; ks < 2; ks++) {
            short8 pf[2];
#pragma unroll
            for (int mi = 0; mi < 2; mi++)
                pf[mi] = *(const short8*)(&Pl[wave][mi * 16 + l15][ks * 32 + quad * 8]);
#pragma unroll
            for (int df = 0; df < 8; df++) {
                short8 vf = *(const short8*)(&Vt[df * 16 + l15][ks * 32 + quad * 8]);
#pragma unroll
                for (int mi = 0; mi < 2; mi++)
                    o[mi][df] = __builtin_amdgcn_mfma_f32_16x16x32_bf16(
                        pf[mi], vf, o[mi][df], 0, 0, 0);
            }
        }
    }

    // epilogue: normalize by l, write bf16
#pragma unroll
    for (int mi = 0; mi < 2; mi++)
#pragma unroll
        for (int r = 0; r < 4; r++) {
            int row = q0 + wave * 32 + mi * 16 + quad * 4 + r;
            float inv = 1.0f / l_run[mi][r];
#pragma unroll
            for (int df = 0; df < 8; df++) {
                float v = o[mi][df][r] * inv;
                out[(size_t)row * (NHEAD * DHEAD) + head * DHEAD + df * 16 + l15] = f2bf(v);
            }
        }
}

// ---------------------------------------------------------------------------
extern "C" void kernel_launch(void* const* d_in, const int* in_sizes, int n_in,
                              void* d_out, int out_size, void* d_ws, size_t ws_size,
                              hipStream_t stream)
{
    const float* x     = (const float*)d_in[0];  // [1,4096,2048] fp32
    const float* wqkv  = (const float*)d_in[1];  // [3072,2048]  fp32
    const float* wproj = (const float*)d_in[2];  // [2048,2048]  fp32
    float* outp = (float*)d_out;                 // [1,4096,2048] fp32

    const size_t n_x     = (size_t)S_LEN * HID_DIM;     // 8388608
    const size_t n_wqkv  = (size_t)TOTAL * HID_DIM;     // 6291456
    const size_t n_wproj = (size_t)HID_DIM * HID_DIM;   // 4194304

    ushort* xb     = (ushort*)d_ws;
    ushort* wqkvb  = xb + n_x;
    ushort* wprojb = wqkvb + n_wqkv;
    ushort* qkv    = wprojb + n_wproj;                  // 4096*3072 bf16
    ushort* attn   = qkv + (size_t)S_LEN * TOTAL;       // 4096*2048 bf16

    // 0) convert fp32 inputs to bf16 staging copies
    cvt_f32_bf16<<<2048, 256, 0, stream>>>(x, xb, (int)(n_x / 4));
    cvt_f32_bf16<<<2048, 256, 0, stream>>>(wqkv, wqkvb, (int)(n_wqkv / 4));
    cvt_f32_bf16<<<2048, 256, 0, stream>>>(wproj, wprojb, (int)(n_wproj / 4));

    // 1) qkv = x @ wqkv^T
    gemm_bt<ushort><<<dim3(TOTAL / 128, S_LEN / 128), 256, 0, stream>>>(
        xb, wqkvb, qkv, S_LEN, TOTAL, HID_DIM);
    // 2) attention
    flash_attn<<<dim3(S_LEN / 128, NHEAD), 256, 0, stream>>>(qkv, attn);
    // 3) out = attn @ wproj^T  (fp32 store)
    gemm_bt<float><<<dim3(HID_DIM / 128, S_LEN / 128), 256, 0, stream>>>(
        attn, wprojb, outp, S_LEN, HID_DIM, HID_DIM);
}

// Round 3
// 520.524 us; speedup vs baseline: 1.3792x; 1.3792x over previous
//
#include <hip/hip_runtime.h>
#include <hip/hip_bf16.h>
#include <stdint.h>

typedef __attribute__((ext_vector_type(8))) short short8;
typedef __attribute__((ext_vector_type(4))) float f32x4;

#define S_LEN   4096
#define HID_DIM 2048
#define NHEAD   16
#define NKV     4
#define DHEAD   128
#define QPG     4
#define GROUP   768   // (QPG+2)*DHEAD
#define TOTAL   3072  // NKV*GROUP

__device__ __forceinline__ ushort f2bf(float f) {
    union { float f; uint32_t u; } c; c.f = f;
    uint32_t u = c.u;
    u += 0x7fff + ((u >> 16) & 1);   // RNE
    return (ushort)(u >> 16);
}

__device__ __forceinline__ void gld_lds16(const void* g, void* l) {
    __builtin_amdgcn_global_load_lds(
        (const __attribute__((address_space(1))) void*)g,
        (__attribute__((address_space(3))) void*)l, 16, 0, 0);
}

// ---------------------------------------------------------------------------
// fp32 -> bf16 convert. mode 1: scale q-head rows of wqkv by 1/sqrt(D)
// (row = element/2048; q rows are (row%768)<512)
// ---------------------------------------------------------------------------
__global__ __launch_bounds__(256)
void cvt_f32_bf16(const float* __restrict__ src, ushort* __restrict__ dst,
                  int n4, int mode)
{
    int i = blockIdx.x * blockDim.x + threadIdx.x;
    int stride = gridDim.x * blockDim.x;
    for (; i < n4; i += stride) {
        float sc = 1.0f;
        if (mode == 1) {
            int row = i >> 9;                      // (i*4)/2048
            sc = ((row % GROUP) < QPG * DHEAD) ? 0.088388347648318447f : 1.0f;
        }
        float4 v = ((const float4*)src)[i];
        ushort4 o;
        o.x = f2bf(v.x * sc); o.y = f2bf(v.y * sc);
        o.z = f2bf(v.z * sc); o.w = f2bf(v.w * sc);
        ((ushort4*)dst)[i] = o;
    }
}

// ---------------------------------------------------------------------------
// C[M,N] = A[M,K] * B[N,K]^T (bf16 in, fp32 accum). m97-style: unpadded LDS +
// global_load_lds width-16 staging. 128x128 tile, BK=32, 4 waves 2x2.
// WRITE_VT: column-blocks in V-region additionally store V^T to VT[g][d][s].
// ---------------------------------------------------------------------------
__device__ __forceinline__ void store_c(ushort* C, size_t idx, float v) { C[idx] = f2bf(v); }
__device__ __forceinline__ void store_c(float*  C, size_t idx, float v) { C[idx] = v; }

template <typename OutT, bool WRITE_VT>
__global__ __launch_bounds__(256, 2)
void gemm_bt(const ushort* __restrict__ A, const ushort* __restrict__ B,
             OutT* __restrict__ C, ushort* __restrict__ VT,
             int M, int N, int K)
{
    __shared__ alignas(16) ushort Asl[128 * 32];
    __shared__ alignas(16) ushort Bsl[128 * 32];

    const int tid  = threadIdx.x;
    const int wave = tid >> 6;
    const int lane = tid & 63;
    const int quad = lane >> 4;
    const int l15  = lane & 15;
    const int wr   = wave >> 1;
    const int wc   = wave & 1;
    const int m0   = blockIdx.y * 128;
    const int n0   = blockIdx.x * 128;

    f32x4 acc[4][4];
#pragma unroll
    for (int i = 0; i < 4; i++)
#pragma unroll
        for (int j = 0; j < 4; j++) acc[i][j] = (f32x4)0.0f;

    for (int kb = 0; kb < K; kb += 32) {
        __syncthreads();
#pragma unroll
        for (int r = 0; r < 2; r++) {
            int idx = tid + r * 256;        // 0..511: row = idx>>2, chunk = idx&3
            int row = idx >> 2, c8 = idx & 3;
            char* la = (char*)Asl + (size_t)(wave * 64 + r * 256) * 16;  // wave-uniform
            char* lb = (char*)Bsl + (size_t)(wave * 64 + r * 256) * 16;
            gld_lds16(A + (size_t)(m0 + row) * K + kb + c8 * 8, la);
            gld_lds16(B + (size_t)(n0 + row) * K + kb + c8 * 8, lb);
        }
        __syncthreads();   // drains vmcnt -> LDS valid

        short8 af[4], bf[4];
#pragma unroll
        for (int i = 0; i < 4; i++)
            af[i] = *(const short8*)(&Asl[(wr * 64 + i * 16 + l15) * 32 + quad * 8]);
#pragma unroll
        for (int j = 0; j < 4; j++)
            bf[j] = *(const short8*)(&Bsl[(wc * 64 + j * 16 + l15) * 32 + quad * 8]);
#pragma unroll
        for (int i = 0; i < 4; i++)
#pragma unroll
            for (int j = 0; j < 4; j++)
                acc[i][j] = __builtin_amdgcn_mfma_f32_16x16x32_bf16(
                    af[i], bf[j], acc[i][j], 0, 0, 0);
    }

    // epilogue: C/D layout col=lane&15, row=quad*4+reg
#pragma unroll
    for (int i = 0; i < 4; i++)
#pragma unroll
        for (int j = 0; j < 4; j++)
#pragma unroll
            for (int r = 0; r < 4; r++) {
                int row = m0 + wr * 64 + i * 16 + quad * 4 + r;
                int col = n0 + wc * 64 + j * 16 + l15;
                store_c(C, (size_t)row * N + col, acc[i][j][r]);
            }

    if (WRITE_VT) {
        int cb = n0 >> 7;
        if (cb % 6 == 5) {          // this 128-col block is a V region
            int g = cb / 6;
#pragma unroll
            for (int i = 0; i < 4; i++)
#pragma unroll
                for (int j = 0; j < 4; j++) {
                    int d    = wc * 64 + j * 16 + l15;            // 0..127
                    int row0 = m0 + wr * 64 + i * 16 + quad * 4;  // 4 consecutive s
                    ushort4 pk;
                    pk.x = f2bf(acc[i][j][0]); pk.y = f2bf(acc[i][j][1]);
                    pk.z = f2bf(acc[i][j][2]); pk.w = f2bf(acc[i][j][3]);
                    *(ushort4*)(VT + (size_t)(g * 128 + d) * S_LEN + row0) = pk;
                }
        }
    }
}

// ---------------------------------------------------------------------------
// Causal GQA flash attention. Q,K from qkv [S,TOTAL] (Q pre-scaled); V^T from
// VT[g][d][s]. Block: 1 head x 128 q-rows, 4 waves x 32 rows. K-tile = 64.
// ---------------------------------------------------------------------------
__global__ __launch_bounds__(256, 2)
void flash_attn(const ushort* __restrict__ qkv, const ushort* __restrict__ VT,
                ushort* __restrict__ out)
{
    const int head = blockIdx.y;
    const int g    = head >> 2;
    const int qh   = head & 3;
    const int qt   = gridDim.x - 1 - blockIdx.x;  // heavy tiles first
    const int q0   = qt * 128;

    const int tid  = threadIdx.x;
    const int wave = tid >> 6;
    const int lane = tid & 63;
    const int quad = lane >> 4;
    const int l15  = lane & 15;

    __shared__ alignas(16) ushort Kl[64][136];    // [j][d]
    __shared__ alignas(16) ushort Vt[128][72];    // [d][j]
    __shared__ alignas(16) ushort Pl[4][32][72];  // per-wave P

    short8 qf[2][4];
#pragma unroll
    for (int mi = 0; mi < 2; mi++) {
        int row = q0 + wave * 32 + mi * 16 + l15;
        const ushort* qp = qkv + (size_t)row * TOTAL + g * GROUP + qh * DHEAD + quad * 8;
#pragma unroll
        for (int ks = 0; ks < 4; ks++)
            qf[mi][ks] = *(const short8*)(qp + ks * 32);
    }

    f32x4 o[2][8];
#pragma unroll
    for (int mi = 0; mi < 2; mi++)
#pragma unroll
        for (int df = 0; df < 8; df++) o[mi][df] = (f32x4)0.0f;

    float m_run[2][4], l_run[2][4];
#pragma unroll
    for (int mi = 0; mi < 2; mi++)
#pragma unroll
        for (int r = 0; r < 4; r++) { m_run[mi][r] = -INFINITY; l_run[mi][r] = 0.0f; }

    const int ntiles = q0 / 64 + 2;

    for (int t = 0; t < ntiles; t++) {
        const int j0 = t * 64;
        __syncthreads();
        // stage K[64][128] (1024 chunks) + V^T[128][64] (1024 chunks), 8/thread
#pragma unroll
        for (int r = 0; r < 4; r++) {
            int c = tid + r * 256;
            int kr = c >> 4, kc = c & 15;
            *(float4*)(&Kl[kr][kc * 8]) = *(const float4*)(
                qkv + (size_t)(j0 + kr) * TOTAL + g * GROUP + QPG * DHEAD + kc * 8);
            int vd = c >> 3, vc = c & 7;
            *(float4*)(&Vt[vd][vc * 8]) = *(const float4*)(
                VT + (size_t)(g * 128 + vd) * S_LEN + j0 + vc * 8);
        }
        __syncthreads();

        // S = Q K^T (pre-scaled)
        f32x4 sacc[2][4];
#pragma unroll
        for (int mi = 0; mi < 2; mi++)
#pragma unroll
            for (int ni = 0; ni < 4; ni++) sacc[mi][ni] = (f32x4)0.0f;
#pragma unroll
        for (int ni = 0; ni < 4; ni++) {
#pragma unroll
            for (int ks = 0; ks < 4; ks++) {
                short8 kf = *(const short8*)(&Kl[ni * 16 + l15][ks * 32 + quad * 8]);
#pragma unroll
                for (int mi = 0; mi < 2; mi++)
                    sacc[mi][ni] = __builtin_amdgcn_mfma_f32_16x16x32_bf16(
                        qf[mi][ks], kf, sacc[mi][ni], 0, 0, 0);
            }
        }

        // online softmax; mask only when tile crosses the diagonal for this mi
#pragma unroll
        for (int mi = 0; mi < 2; mi++) {
            const int base = q0 + wave * 32 + mi * 16;     // wave-uniform
            const bool need_mask = (j0 + 63 > base);
            float alpha[4];
#pragma unroll
            for (int r = 0; r < 4; r++) {
                float mx = -3e38f;
                if (need_mask) {
                    int row_g = base + quad * 4 + r;
#pragma unroll
                    for (int ni = 0; ni < 4; ni++) {
                        int col_g = j0 + ni * 16 + l15;
                        float s = sacc[mi][ni][r];
                        s = (col_g > row_g) ? -3e38f : s;
                        sacc[mi][ni][r] = s;
                        mx = fmaxf(mx, s);
                    }
                } else {
#pragma unroll
                    for (int ni = 0; ni < 4; ni++) mx = fmaxf(mx, sacc[mi][ni][r]);
                }
                mx = fmaxf(mx, __shfl_xor(mx, 1));
                mx = fmaxf(mx, __shfl_xor(mx, 2));
                mx = fmaxf(mx, __shfl_xor(mx, 4));
                mx = fmaxf(mx, __shfl_xor(mx, 8));
                float mn = fmaxf(m_run[mi][r], mx);
                float al = __expf(m_run[mi][r] - mn);
                float rs = 0.0f;
#pragma unroll
                for (int ni = 0; ni < 4; ni++) {
                    float p = __expf(sacc[mi][ni][r] - mn);
                    sacc[mi][ni][r] = p;
                    rs += p;
                }
                rs += __shfl_xor(rs, 1);
                rs += __shfl_xor(rs, 2);
                rs += __shfl_xor(rs, 4);
                rs += __shfl_xor(rs, 8);
                l_run[mi][r] = l_run[mi][r] * al + rs;
                m_run[mi][r] = mn;
                alpha[r] = al;
            }
#pragma unroll
            for (int df = 0; df < 8; df++)
#pragma unroll
                for (int r = 0; r < 4; r++) o[mi][df][r] *= alpha[r];
#pragma unroll
            for (int ni = 0; ni < 4; ni++)
#pragma unroll
                for (int r = 0; r < 4; r++)
                    Pl[wave][mi * 16 + quad * 4 + r][ni * 16 + l15] =
                        f2bf(sacc[mi][ni][r]);
        }
        __syncthreads();

        // O += P V
#pragma unroll
        for (int ks = 0; ks < 2; ks++) {
            short8 pf[2];
#pragma unroll
            for (int mi = 0; mi < 2; mi++)
                pf[mi] = *(const short8*)(&Pl[wave][mi * 16 + l15][ks * 32 + quad * 8]);
#pragma unroll
            for (int df = 0; df < 8; df++) {
                short8 vf = *(const short8*)(&Vt[df * 16 + l15][ks * 32 + quad * 8]);
#pragma unroll
                for (int mi = 0; mi < 2; mi++)
                    o[mi][df] = __builtin_amdgcn_mfma_f32_16x16x32_bf16(
                        pf[mi], vf, o[mi][df], 0, 0, 0);
            }
        }
    }

#pragma unroll
    for (int mi = 0; mi < 2; mi++)
#pragma unroll
        for (int r = 0; r < 4; r++) {
            int row = q0 + wave * 32 + mi * 16 + quad * 4 + r;
            float inv = 1.0f / l_run[mi][r];
#pragma unroll
            for (int df = 0; df < 8; df++) {
                float v = o[mi][df][r] * inv;
                out[(size_t)row * (NHEAD * DHEAD) + head * DHEAD + df * 16 + l15] = f2bf(v);
            }
        }
}

// ---------------------------------------------------------------------------
extern "C" void kernel_launch(void* const* d_in, const int* in_sizes, int n_in,
                              void* d_out, int out_size, void* d_ws, size_t ws_size,
                              hipStream_t stream)
{
    const float* x     = (const float*)d_in[0];
    const float* wqkv  = (const float*)d_in[1];
    const float* wproj = (const float*)d_in[2];
    float* outp = (float*)d_out;

    const size_t n_x     = (size_t)S_LEN * HID_DIM;     // 8388608
    const size_t n_wqkv  = (size_t)TOTAL * HID_DIM;     // 6291456
    const size_t n_wproj = (size_t)HID_DIM * HID_DIM;   // 4194304
    const size_t n_qkv   = (size_t)S_LEN * TOTAL;       // 12582912
    const size_t n_attn  = (size_t)S_LEN * HID_DIM;     // 8388608

    ushort* xb     = (ushort*)d_ws;                     // dead after GEMM1
    ushort* wqkvb  = xb + n_x;
    ushort* qkv    = wqkvb + n_wqkv;
    ushort* attn   = qkv + n_qkv;
    ushort* vt     = attn + n_attn;                     // [4][128][4096]
    ushort* wprojb = xb;                                // aliases dead xb

    cvt_f32_bf16<<<2048, 256, 0, stream>>>(x, xb, (int)(n_x / 4), 0);
    cvt_f32_bf16<<<2048, 256, 0, stream>>>(wqkv, wqkvb, (int)(n_wqkv / 4), 1);

    // 1) qkv = x @ wqkv^T (+ V^T side-write)
    gemm_bt<ushort, true><<<dim3(TOTAL / 128, S_LEN / 128), 256, 0, stream>>>(
        xb, wqkvb, qkv, vt, S_LEN, TOTAL, HID_DIM);

    // convert wproj into the space xb occupied (xb now dead)
    cvt_f32_bf16<<<2048, 256, 0, stream>>>(wproj, wprojb, (int)(n_wproj / 4), 0);

    // 2) attention
    flash_attn<<<dim3(S_LEN / 128, NHEAD), 256, 0, stream>>>(qkv, vt, attn);

    // 3) out = attn @ wproj^T (fp32 store)
    gemm_bt<float, false><<<dim3(HID_DIM / 128, S_LEN / 128), 256, 0, stream>>>(
        attn, wprojb, outp, nullptr, S_LEN, HID_DIM, HID_DIM);
}